// Round 6
// baseline (171.562 us; speedup 1.0000x reference)
//
#include <hip/hip_runtime.h>
#include <stdint.h>

// random_masking: out = input, except channels {0,10,...,90} of each batch are
// replaced with jax.random.normal(jax.random.key(1), (4, 10, 512*512)).
// PRNG path (verified R1, absmax 1.5e-2 vs 1.08e-1 threshold): partitionable
// Threefry-2x32 + XLA Giles erfinv. DO NOT change numerics.
//
// R6 = DECOMPOSITION experiment. Two sequential kernels:
//   B (noise): 10 channels, 1 f4/thread, 2560 blocks — VALU-bound, ~15us.
//   A (copy):  90 channels, R2's proven copy-block structure (2048-f4 tile,
//              8-deep nt), 11520 blocks, ZERO PRNG code — pure m13-clone.
// Purpose: measure whether the copy stream alone reaches the 6.29 TB/s plain-
// copy ceiling (total ~138us) or is itself stuck at 5.25 (total ~157).
// History: R2(nt,clustered)=151.5  R4(nt,woven)=152.6  R5(plain)=159.7 regress.

typedef float f32x4 __attribute__((ext_vector_type(4)));

__device__ __forceinline__ uint32_t rotl32(uint32_t v, int r) {
    return (v << r) | (v >> (32 - r));
}

// Threefry-2x32, key = (0, 1)  [jax.random.key(1)]
__device__ __forceinline__ void threefry2x32_key01(uint32_t x0, uint32_t x1,
                                                   uint32_t& o0, uint32_t& o1) {
    const uint32_t ks0 = 0u;
    const uint32_t ks1 = 1u;
    const uint32_t ks2 = 0x1BD11BDAu ^ ks0 ^ ks1;  // 0x1BD11BDB
    x0 += ks0; x1 += ks1;
#define TF_R(r) { x0 += x1; x1 = rotl32(x1, (r)); x1 ^= x0; }
    TF_R(13) TF_R(15) TF_R(26) TF_R(6)
    x0 += ks1; x1 += ks2 + 1u;
    TF_R(17) TF_R(29) TF_R(16) TF_R(24)
    x0 += ks2; x1 += ks0 + 2u;
    TF_R(13) TF_R(15) TF_R(26) TF_R(6)
    x0 += ks0; x1 += ks1 + 3u;
    TF_R(17) TF_R(29) TF_R(16) TF_R(24)
    x0 += ks1; x1 += ks2 + 4u;
    TF_R(13) TF_R(15) TF_R(26) TF_R(6)
    x0 += ks2; x1 += ks0 + 5u;
#undef TF_R
    o0 = x0; o1 = x1;
}

// XLA f32 ErfInv (Giles polynomial) — identical coefficients to xla math.cc
__device__ __forceinline__ float erfinv_xla_f32(float x) {
    float w = -log1pf(-x * x);
    float p;
    if (w < 5.0f) {
        w = w - 2.5f;
        p = 2.81022636e-08f;
        p = fmaf(p, w, 3.43273939e-07f);
        p = fmaf(p, w, -3.5233877e-06f);
        p = fmaf(p, w, -4.39150654e-06f);
        p = fmaf(p, w, 0.00021858087f);
        p = fmaf(p, w, -0.00125372503f);
        p = fmaf(p, w, -0.00417768164f);
        p = fmaf(p, w, 0.246640727f);
        p = fmaf(p, w, 1.50140941f);
    } else {
        w = sqrtf(w) - 3.0f;
        p = -0.000200214257f;
        p = fmaf(p, w, 0.000100950558f);
        p = fmaf(p, w, 0.00134934322f);
        p = fmaf(p, w, -0.00367342844f);
        p = fmaf(p, w, 0.00573950773f);
        p = fmaf(p, w, -0.0076224613f);
        p = fmaf(p, w, 0.00943887047f);
        p = fmaf(p, w, 1.00167406f);
        p = fmaf(p, w, 2.83297682f);
    }
    return p * x;
}

// bits -> uniform(nextafter(-1,0), 1) -> sqrt(2)*erfinv(u), matching JAX normal()
__device__ __forceinline__ float bits_to_normal(uint32_t bits) {
    float f = __uint_as_float((bits >> 9) | 0x3F800000u) - 1.0f;  // [0, 1)
    const float lo = __uint_as_float(0xBF7FFFFFu);                // nextafter(-1f, 0)
    float u = f * 2.0f + lo;   // exact: f*2 is a pow2 scale, sum representable
    u = fmaxf(lo, u);
    const float sqrt2 = __uint_as_float(0x3FB504F3u);             // float32(sqrt(2))
    return sqrt2 * erfinv_xla_f32(u);
}

// ---------------- Kernel B: noise fill (10 channels, VALU-bound) ----------
// Noise channels cb = grp*10, grp in [0,40). Noise-array flat channel == grp.
// 40 * 65536 f4 = 2,621,440 f4 ... wait: 10 sel * 4 batches = 40 channel
// instances * 65536 f4 = 2,621,440 f4 / 256 threads = 10240 blocks of 1 f4.
// Use 4 f4 per thread -> 2560 blocks.
constexpr uint32_t NBLK_B = 2560;

__global__ __launch_bounds__(256) void noise_kernel(f32x4* __restrict__ out) {
    // each thread: 4 f4, consecutive threads consecutive 16B (k spreads 256)
    const uint32_t tbase = (blockIdx.x << 10) + threadIdx.x;  // f4 index / k-stride 256
#pragma unroll
    for (int k = 0; k < 4; ++k) {
        const uint32_t idx  = tbase + k * 256;       // [0, 2621440)
        const uint32_t grp  = idx >> 16;             // 0..39
        const uint32_t off4 = idx & 65535u;
        const uint32_t j    = (grp << 18) | (off4 << 2);
        f32x4 o;
#pragma unroll
        for (int e = 0; e < 4; ++e) {
            uint32_t y0, y1;
            threefry2x32_key01(0u, j + (uint32_t)e, y0, y1);
            o[e] = bits_to_normal(y0 ^ y1);
        }
        __builtin_nontemporal_store(o, out + (grp * 10u << 16) + off4);
    }
}

// ---------------- Kernel A: pure copy (90 channels, m13-clone) ------------
// Copy channels: cb%10 in {1..9}. cc in [0,360) -> cb = (cc/9)*10 + cc%9 + 1.
// Tile = 2048 f4, 32 tiles/channel -> 11520 blocks, 8-deep nt.
constexpr uint32_t NBLK_A = 360u * 32u;

__global__ __launch_bounds__(256) void copy_kernel(
        const f32x4* __restrict__ in, f32x4* __restrict__ out) {
    const uint32_t bid  = blockIdx.x;
    const uint32_t cc   = bid >> 5;                  // 0..359
    const uint32_t tile = bid & 31u;
    const uint32_t g    = cc / 9u;
    const uint32_t cb   = g * 10u + (cc - g * 9u) + 1u;
    const uint32_t base = (cb << 16) + (tile << 11) + threadIdx.x;

    f32x4 v[8];
#pragma unroll
    for (int k = 0; k < 8; ++k)
        v[k] = __builtin_nontemporal_load(in + base + k * 256);
#pragma unroll
    for (int k = 0; k < 8; ++k)
        __builtin_nontemporal_store(v[k], out + base + k * 256);
}

extern "C" void kernel_launch(void* const* d_in, const int* in_sizes, int n_in,
                              void* d_out, int out_size, void* d_ws, size_t ws_size,
                              hipStream_t stream) {
    const f32x4* in = reinterpret_cast<const f32x4*>(d_in[0]);
    f32x4* out = reinterpret_cast<f32x4*>(d_out);
    noise_kernel<<<NBLK_B, 256, 0, stream>>>(out);
    copy_kernel<<<NBLK_A, 256, 0, stream>>>(in, out);
}

// Round 7
// 154.623 us; speedup vs baseline: 1.1095x; 1.1095x over previous
//
#include <hip/hip_runtime.h>
#include <stdint.h>

// random_masking: out = input, except channels {0,10,...,90} of each batch are
// replaced with jax.random.normal(jax.random.key(1), (4, 10, 512*512)).
// PRNG path (verified R1, absmax 1.5e-2 vs 1.08e-1 threshold): partitionable
// Threefry-2x32 + XLA Giles erfinv. DO NOT change numerics.
//
// R7 = R4 (best, 152.6us) with ONE variable: loads nt->plain. Stores stay nt.
// Hint matrix so far: nt/nt=152.6  plain/plain=159.7  -> testing plain/nt.
// Evidence: R6 split showed pure copy (no PRNG) runs ~5.0 TB/s => limiter is
// memory-path policy, not noise overlap. m13's 6.29 TB/s copy used plain loads.

typedef float f32x4 __attribute__((ext_vector_type(4)));

__device__ __forceinline__ uint32_t rotl32(uint32_t v, int r) {
    return (v << r) | (v >> (32 - r));
}

// Threefry-2x32, key = (0, 1)  [jax.random.key(1)]
__device__ __forceinline__ void threefry2x32_key01(uint32_t x0, uint32_t x1,
                                                   uint32_t& o0, uint32_t& o1) {
    const uint32_t ks0 = 0u;
    const uint32_t ks1 = 1u;
    const uint32_t ks2 = 0x1BD11BDAu ^ ks0 ^ ks1;  // 0x1BD11BDB
    x0 += ks0; x1 += ks1;
#define TF_R(r) { x0 += x1; x1 = rotl32(x1, (r)); x1 ^= x0; }
    TF_R(13) TF_R(15) TF_R(26) TF_R(6)
    x0 += ks1; x1 += ks2 + 1u;
    TF_R(17) TF_R(29) TF_R(16) TF_R(24)
    x0 += ks2; x1 += ks0 + 2u;
    TF_R(13) TF_R(15) TF_R(26) TF_R(6)
    x0 += ks0; x1 += ks1 + 3u;
    TF_R(17) TF_R(29) TF_R(16) TF_R(24)
    x0 += ks1; x1 += ks2 + 4u;
    TF_R(13) TF_R(15) TF_R(26) TF_R(6)
    x0 += ks2; x1 += ks0 + 5u;
#undef TF_R
    o0 = x0; o1 = x1;
}

// XLA f32 ErfInv (Giles polynomial) — identical coefficients to xla math.cc
__device__ __forceinline__ float erfinv_xla_f32(float x) {
    float w = -log1pf(-x * x);
    float p;
    if (w < 5.0f) {
        w = w - 2.5f;
        p = 2.81022636e-08f;
        p = fmaf(p, w, 3.43273939e-07f);
        p = fmaf(p, w, -3.5233877e-06f);
        p = fmaf(p, w, -4.39150654e-06f);
        p = fmaf(p, w, 0.00021858087f);
        p = fmaf(p, w, -0.00125372503f);
        p = fmaf(p, w, -0.00417768164f);
        p = fmaf(p, w, 0.246640727f);
        p = fmaf(p, w, 1.50140941f);
    } else {
        w = sqrtf(w) - 3.0f;
        p = -0.000200214257f;
        p = fmaf(p, w, 0.000100950558f);
        p = fmaf(p, w, 0.00134934322f);
        p = fmaf(p, w, -0.00367342844f);
        p = fmaf(p, w, 0.00573950773f);
        p = fmaf(p, w, -0.0076224613f);
        p = fmaf(p, w, 0.00943887047f);
        p = fmaf(p, w, 1.00167406f);
        p = fmaf(p, w, 2.83297682f);
    }
    return p * x;
}

// bits -> uniform(nextafter(-1,0), 1) -> sqrt(2)*erfinv(u), matching JAX normal()
__device__ __forceinline__ float bits_to_normal(uint32_t bits) {
    float f = __uint_as_float((bits >> 9) | 0x3F800000u) - 1.0f;  // [0, 1)
    const float lo = __uint_as_float(0xBF7FFFFFu);                // nextafter(-1f, 0)
    float u = f * 2.0f + lo;   // exact: f*2 is a pow2 scale, sum representable
    u = fmaxf(lo, u);
    const float sqrt2 = __uint_as_float(0x3FB504F3u);             // float32(sqrt(2))
    return sqrt2 * erfinv_xla_f32(u);
}

// Geometry: (4,100,512,512) f32. Channel = 65536 f4. Group = 10 channels
// (cb0 = grp*10 is noise; +1..+9 are copies). Tile = 2048 f4 => 32 tiles/group,
// 40 groups => 1280 blocks = 5/CU exactly, single co-resident pass.
constexpr uint32_t NBLOCKS = 40u * 32u;

__global__ __launch_bounds__(256, 5) void random_masking_kernel(
        const f32x4* __restrict__ in, f32x4* __restrict__ out) {
    const uint32_t bid   = blockIdx.x;
    const uint32_t grp   = bid >> 5;                   // 0..39  (== b*10 + s)
    const uint32_t tile  = bid & 31u;
    const uint32_t cb0   = grp * 10u;                  // noise channel (b*100+c)
    const uint32_t off   = (tile << 11) + threadIdx.x; // f4 offset in channel
    const uint32_t jch   = grp << 18;                  // noise-array channel base
    const uint32_t base0 = (cb0 << 16) + off;

    for (uint32_t ch = 1; ch <= 9; ++ch) {
        const f32x4* src = in  + base0 + (ch << 16);
        f32x4*       dst = out + base0 + (ch << 16);

        // issue 8 independent PLAIN (L2/L3-allocating) loads for this channel
        f32x4 v[8];
#pragma unroll
        for (int k = 0; k < 8; ++k)
            v[k] = src[k * 256];

        // one noise f4 per iteration (8 total over ch=1..8), overlapping the
        // outstanding loads — pure VALU, no memory dependence
        if (ch <= 8) {
            const uint32_t q = ch - 1;
            const uint32_t j = jch + ((off + q * 256u) << 2);
            f32x4 o;
#pragma unroll
            for (int e = 0; e < 4; ++e) {
                uint32_t y0, y1;
                threefry2x32_key01(0u, j + (uint32_t)e, y0, y1);
                o[e] = bits_to_normal(y0 ^ y1);
            }
            __builtin_nontemporal_store(o, out + base0 + q * 256);
        }

        // store the copied channel (nt — streaming, no write-allocate churn)
#pragma unroll
        for (int k = 0; k < 8; ++k)
            __builtin_nontemporal_store(v[k], dst + k * 256);
    }
}

extern "C" void kernel_launch(void* const* d_in, const int* in_sizes, int n_in,
                              void* d_out, int out_size, void* d_ws, size_t ws_size,
                              hipStream_t stream) {
    const f32x4* in = reinterpret_cast<const f32x4*>(d_in[0]);
    f32x4* out = reinterpret_cast<f32x4*>(d_out);
    random_masking_kernel<<<NBLOCKS, 256, 0, stream>>>(in, out);
}

// Round 8
// 152.706 us; speedup vs baseline: 1.1235x; 1.0126x over previous
//
#include <hip/hip_runtime.h>
#include <stdint.h>

// random_masking: out = input, except channels {0,10,...,90} of each batch are
// replaced with jax.random.normal(jax.random.key(1), (4, 10, 512*512)).
// PRNG path (verified R1, absmax 1.5e-2 vs 1.08e-1 threshold): partitionable
// Threefry-2x32 + XLA Giles erfinv. DO NOT change numerics.
//
// R8 = FINAL: exact revert to R4 (best measured, 152.6us = 5.22 TB/s).
// Ceiling evidence (R1-R7): hint matrix nt/nt=152.6 < plain/nt=154.6 <
// plain/plain=159.7; R6 decomposition showed a pure 8-deep nt copy (no PRNG)
// caps at ~5.0 TB/s on these buffers => fused kernel exceeds the naked copy
// rate; 5.2/7.0 write-only = 0.75 = mixed-stream bus-turnaround discount.
// 797 MB irreducible traffic, zero reuse. This is the roofline.

typedef float f32x4 __attribute__((ext_vector_type(4)));

__device__ __forceinline__ uint32_t rotl32(uint32_t v, int r) {
    return (v << r) | (v >> (32 - r));
}

// Threefry-2x32, key = (0, 1)  [jax.random.key(1)]
__device__ __forceinline__ void threefry2x32_key01(uint32_t x0, uint32_t x1,
                                                   uint32_t& o0, uint32_t& o1) {
    const uint32_t ks0 = 0u;
    const uint32_t ks1 = 1u;
    const uint32_t ks2 = 0x1BD11BDAu ^ ks0 ^ ks1;  // 0x1BD11BDB
    x0 += ks0; x1 += ks1;
#define TF_R(r) { x0 += x1; x1 = rotl32(x1, (r)); x1 ^= x0; }
    TF_R(13) TF_R(15) TF_R(26) TF_R(6)
    x0 += ks1; x1 += ks2 + 1u;
    TF_R(17) TF_R(29) TF_R(16) TF_R(24)
    x0 += ks2; x1 += ks0 + 2u;
    TF_R(13) TF_R(15) TF_R(26) TF_R(6)
    x0 += ks0; x1 += ks1 + 3u;
    TF_R(17) TF_R(29) TF_R(16) TF_R(24)
    x0 += ks1; x1 += ks2 + 4u;
    TF_R(13) TF_R(15) TF_R(26) TF_R(6)
    x0 += ks2; x1 += ks0 + 5u;
#undef TF_R
    o0 = x0; o1 = x1;
}

// XLA f32 ErfInv (Giles polynomial) — identical coefficients to xla math.cc
__device__ __forceinline__ float erfinv_xla_f32(float x) {
    float w = -log1pf(-x * x);
    float p;
    if (w < 5.0f) {
        w = w - 2.5f;
        p = 2.81022636e-08f;
        p = fmaf(p, w, 3.43273939e-07f);
        p = fmaf(p, w, -3.5233877e-06f);
        p = fmaf(p, w, -4.39150654e-06f);
        p = fmaf(p, w, 0.00021858087f);
        p = fmaf(p, w, -0.00125372503f);
        p = fmaf(p, w, -0.00417768164f);
        p = fmaf(p, w, 0.246640727f);
        p = fmaf(p, w, 1.50140941f);
    } else {
        w = sqrtf(w) - 3.0f;
        p = -0.000200214257f;
        p = fmaf(p, w, 0.000100950558f);
        p = fmaf(p, w, 0.00134934322f);
        p = fmaf(p, w, -0.00367342844f);
        p = fmaf(p, w, 0.00573950773f);
        p = fmaf(p, w, -0.0076224613f);
        p = fmaf(p, w, 0.00943887047f);
        p = fmaf(p, w, 1.00167406f);
        p = fmaf(p, w, 2.83297682f);
    }
    return p * x;
}

// bits -> uniform(nextafter(-1,0), 1) -> sqrt(2)*erfinv(u), matching JAX normal()
__device__ __forceinline__ float bits_to_normal(uint32_t bits) {
    float f = __uint_as_float((bits >> 9) | 0x3F800000u) - 1.0f;  // [0, 1)
    const float lo = __uint_as_float(0xBF7FFFFFu);                // nextafter(-1f, 0)
    float u = f * 2.0f + lo;   // exact: f*2 is a pow2 scale, sum representable
    u = fmaxf(lo, u);
    const float sqrt2 = __uint_as_float(0x3FB504F3u);             // float32(sqrt(2))
    return sqrt2 * erfinv_xla_f32(u);
}

// Geometry: (4,100,512,512) f32. Channel = 65536 f4. Group = 10 channels
// (cb0 = grp*10 is noise; +1..+9 are copies). Tile = 2048 f4 => 32 tiles/group,
// 40 groups => 1280 blocks = 5/CU exactly, single co-resident pass.
constexpr uint32_t NBLOCKS = 40u * 32u;

__global__ __launch_bounds__(256, 5) void random_masking_kernel(
        const f32x4* __restrict__ in, f32x4* __restrict__ out) {
    const uint32_t bid   = blockIdx.x;
    const uint32_t grp   = bid >> 5;                   // 0..39  (== b*10 + s)
    const uint32_t tile  = bid & 31u;
    const uint32_t cb0   = grp * 10u;                  // noise channel (b*100+c)
    const uint32_t off   = (tile << 11) + threadIdx.x; // f4 offset in channel
    const uint32_t jch   = grp << 18;                  // noise-array channel base
    const uint32_t base0 = (cb0 << 16) + off;

    for (uint32_t ch = 1; ch <= 9; ++ch) {
        const f32x4* src = in  + base0 + (ch << 16);
        f32x4*       dst = out + base0 + (ch << 16);

        // issue 8 independent nt loads for this copy channel
        f32x4 v[8];
#pragma unroll
        for (int k = 0; k < 8; ++k)
            v[k] = __builtin_nontemporal_load(src + k * 256);

        // one noise f4 per iteration (8 total over ch=1..8), overlapping the
        // outstanding loads — pure VALU, no memory dependence
        if (ch <= 8) {
            const uint32_t q = ch - 1;
            const uint32_t j = jch + ((off + q * 256u) << 2);
            f32x4 o;
#pragma unroll
            for (int e = 0; e < 4; ++e) {
                uint32_t y0, y1;
                threefry2x32_key01(0u, j + (uint32_t)e, y0, y1);
                o[e] = bits_to_normal(y0 ^ y1);
            }
            __builtin_nontemporal_store(o, out + base0 + q * 256);
        }

        // store the copied channel (compiler waits vmcnt here, after the VALU)
#pragma unroll
        for (int k = 0; k < 8; ++k)
            __builtin_nontemporal_store(v[k], dst + k * 256);
    }
}

extern "C" void kernel_launch(void* const* d_in, const int* in_sizes, int n_in,
                              void* d_out, int out_size, void* d_ws, size_t ws_size,
                              hipStream_t stream) {
    const f32x4* in = reinterpret_cast<const f32x4*>(d_in[0]);
    f32x4* out = reinterpret_cast<f32x4*>(d_out);
    random_masking_kernel<<<NBLOCKS, 256, 0, stream>>>(in, out);
}